// Round 6
// baseline (1893.776 us; speedup 1.0000x reference)
//
#include <hip/hip_runtime.h>
#include <hip/hip_bf16.h>

#define T 256
#define H 400
#define G4 1600   // 4*H
#define WD 300
#define TD 100
#define MLP_H 400
#define NBLK 25         // blocks total; each handles BOTH directions
#define HB 16           // h-rows per block (per direction)
#define GR 64           // gate-rows per block per direction (4*HB)
#define WSTR 202        // LDS weight row stride in u32 (bank-conflict pad)
#define NPAIR 200       // 400 h values -> 200 tagged 64-bit words per dir

typedef _Float16 f16;
typedef _Float16 half2t __attribute__((ext_vector_type(2)));
typedef unsigned long long u64;
typedef unsigned int u32;

// ---------- math helpers ----------
__device__ __forceinline__ float fexp(float x) {
    return __builtin_amdgcn_exp2f(x * 1.4426950408889634f);
}
__device__ __forceinline__ float sigf(float x) {
    return __builtin_amdgcn_rcpf(1.0f + fexp(-x));
}
__device__ __forceinline__ float tanhf_fast(float x) {
    return 1.0f - 2.0f * __builtin_amdgcn_rcpf(1.0f + fexp(2.0f * x));
}
__device__ __forceinline__ unsigned short f16bits(f16 x) {
    union { f16 h; unsigned short u; } v; v.h = x; return v.u;
}
__device__ __forceinline__ u32 packh2(float a, float b) {
    half2t hv; hv.x = (_Float16)a; hv.y = (_Float16)b;
    return __builtin_bit_cast(u32, hv);
}

#if __has_builtin(__builtin_amdgcn_fdot2)
__device__ __forceinline__ float dot2u(u32 a, u32 b, float c) {
    return __builtin_amdgcn_fdot2(__builtin_bit_cast(half2t, a),
                                  __builtin_bit_cast(half2t, b), c, false);
}
#else
__device__ __forceinline__ float dot2u(u32 a, u32 b, float c) {
    half2t x = __builtin_bit_cast(half2t, a), y = __builtin_bit_cast(half2t, b);
    return fmaf((float)x.y, (float)y.y, fmaf((float)x.x, (float)y.x, c));
}
#endif

// system-scope (sc0 sc1) plain ops: bypass L1/L2, serviced at the IC --
// coherent across XCDs without RMWs or fences. (R0-proven transport.)
__device__ __forceinline__ u64 sysload(const u64* p) {
    return __hip_atomic_load(p, __ATOMIC_RELAXED, __HIP_MEMORY_SCOPE_SYSTEM);
}
__device__ __forceinline__ void sysstore(u64* p, u64 v) {
    __hip_atomic_store(p, v, __ATOMIC_RELAXED, __HIP_MEMORY_SCOPE_SYSTEM);
}

// ---------- embedding gather ----------
__global__ void gather_k(const int* __restrict__ words, const int* __restrict__ tags,
                         const float* __restrict__ wemb, const float* __restrict__ temb,
                         float* __restrict__ x0) {
    int t = blockIdx.x;
    int w = words[t], g = tags[t];
    for (int c = threadIdx.x; c < H; c += 128) {
        float v = (c < WD) ? wemb[w * WD + c] : temb[g * TD + (c - WD)];
        x0[t * H + c] = v;
    }
}

// ---------- generic GEMM: out[t][r] = sum_k X[t*ldx+k]*W[r*ldw+wofs+k] + bias1[r]+bias2[r]
__global__ __launch_bounds__(256) void gemm_tn(
    const float* __restrict__ X, int ldx,
    const float* __restrict__ Wt, int ldw, int wofs,
    const float* __restrict__ bias1, const float* __restrict__ bias2,
    float* __restrict__ out, int ldo, int Rt, int K) {
    __shared__ float Xs[64][17];
    __shared__ float Ws[64][17];
    const int tid = threadIdx.x;
    const int t0 = blockIdx.x * 64, r0 = blockIdx.y * 64;
    const int lr = tid >> 2, kq = (tid & 3) * 4;
    const int ti = tid >> 4, rj = tid & 15;
    float acc[4][4] = {};
    for (int k0 = 0; k0 < K; k0 += 16) {
        float4 xv = *(const float4*)(X + (size_t)(t0 + lr) * ldx + k0 + kq);
        Xs[lr][kq + 0] = xv.x; Xs[lr][kq + 1] = xv.y;
        Xs[lr][kq + 2] = xv.z; Xs[lr][kq + 3] = xv.w;
        int r = r0 + lr;
        float4 wv = make_float4(0.f, 0.f, 0.f, 0.f);
        if (r < Rt) wv = *(const float4*)(Wt + (size_t)r * ldw + wofs + k0 + kq);
        Ws[lr][kq + 0] = wv.x; Ws[lr][kq + 1] = wv.y;
        Ws[lr][kq + 2] = wv.z; Ws[lr][kq + 3] = wv.w;
        __syncthreads();
#pragma unroll
        for (int k = 0; k < 16; k++) {
            float xr[4], wr[4];
#pragma unroll
            for (int m = 0; m < 4; m++) xr[m] = Xs[ti * 4 + m][k];
#pragma unroll
            for (int n = 0; n < 4; n++) wr[n] = Ws[rj * 4 + n][k];
#pragma unroll
            for (int m = 0; m < 4; m++)
#pragma unroll
                for (int n = 0; n < 4; n++)
                    acc[m][n] = fmaf(xr[m], wr[n], acc[m][n]);
        }
        __syncthreads();
    }
    int rq = r0 + rj * 4;
    if (rq < Rt) {
        float b[4];
#pragma unroll
        for (int n = 0; n < 4; n++) {
            int r = rq + n;
            b[n] = (bias1 ? bias1[r] : 0.f) + (bias2 ? bias2[r] : 0.f);
        }
#pragma unroll
        for (int m = 0; m < 4; m++) {
            int t = t0 + ti * 4 + m;
            float4 o;
            o.x = acc[m][0] + b[0]; o.y = acc[m][1] + b[1];
            o.z = acc[m][2] + b[2]; o.w = acc[m][3] + b[3];
            *(float4*)(out + (size_t)t * ldo + rq) = o;
        }
    }
}

// ---------- init: tagged words, contiguous [dir][parity][NPAIR] ----------
__global__ void lstm_init5(const float* __restrict__ h0, u64* sA, u64* sB) {
    int tid = threadIdx.x;
    const int TOT = 2 * 2 * NPAIR;
    for (int i = tid; i < TOT; i += 256) { sA[i] = 0xFFFFULL; sB[i] = 0xFFFFULL; }
    __syncthreads();
    for (int p = tid; p < 2 * NPAIR; p += 256) {
        int d = p / NPAIR, pr = p - d * NPAIR;
        size_t off = (size_t)(d * 2 + 0) * NPAIR + pr;   // parity 0, tag 0
        f16 a0 = (f16)h0[d * H + 2 * pr], b0 = (f16)h0[d * H + 2 * pr + 1];
        sA[off] = 0ULL | ((u64)f16bits(a0) << 16) | ((u64)f16bits(b0) << 32);
        f16 a1 = (f16)h0[2 * H + d * H + 2 * pr], b1 = (f16)h0[2 * H + d * H + 2 * pr + 1];
        sB[off] = 0ULL | ((u64)f16bits(a1) << 16) | ((u64)f16bits(b1) << 32);
    }
}

// ---------- persistent LSTM layer v14: single-barrier pipelined phases ----------
// grid = 25 blocks, 512 threads; each block owns h-rows [blk*16,+16) for BOTH
// directions (weights 101 KiB LDS). 2T+1 phases, ONE __syncthreads each.
// Phase p: workers (tid<256) matvec dir d=p&1 step s=p>>1 -> gsum[d];
//          pollers (256..447) fetch the words workers need at phase p+1
//            (p odd: fwd tag (p-1)/2+1; p even: bwd tag p/2) -- these are
//            published in the SAME phase by other blocks' wave7, so detect
//            latency hides under the matvec;
//          wave7 (448..511) does gate math for the OTHER dir (whose gsum was
//            written last phase), holding c-state AND G (self-prefetched,
//            replacing the stager role) in registers, and publishes
//            immediately -> no serialized gate segment, no second barrier.
// Hazards: hshF written odd/read even phases (hshB reverse); gsum[0]/gsum[1]
// alternate writer/reader phases; all separated by the phase barrier.
// Skew <=1 phase by the R0 induction (barrier waits on all foreign words);
// parity clobber needs 4-phase skew -> safe. Liveness: wave7's publish at
// phase p depends only on intra-block state from p-1, never on phase-p input.
__global__ __launch_bounds__(512, 1) void lstm_layer_dual(
    const float* __restrict__ G,     // [2][T][G4] gate inputs, biases folded
    const float* __restrict__ Whh,   // [2][G4][H]
    const float* __restrict__ c0l,   // [2][H] this layer
    float* __restrict__ xout,        // [T][2H]
    u64* __restrict__ slots) {       // [2][2][NPAIR]
    const int blk = blockIdx.x;
    const int tid = threadIdx.x;
    u64* sdF = slots;
    u64* sdB = slots + 2 * NPAIR;

    __shared__ u32 wlds[2][GR * WSTR];           // 2 x 50.5 KiB = 101 KiB
    __shared__ __align__(16) u32 hshF[NPAIR];    // fwd h (200 packed half2)
    __shared__ __align__(16) u32 hshB[NPAIR];    // bwd h
    __shared__ float gsum[2][GR];                // per-dir matvec sums

    // ---- one-time: pack weights fp32 -> half2 into LDS (both dirs) ----
    for (int idx = tid; idx < 2 * GR * 100; idx += 512) {
        int d = idx / (GR * 100), rem = idx - d * (GR * 100);
        int row = rem / 100, c4 = rem - row * 100;
        int g = row >> 4, r = row & 15;
        const float4* src = (const float4*)(
            Whh + (size_t)d * G4 * H + (size_t)(g * H + blk * HB + r) * H);
        float4 f = src[c4];
        *(uint2*)&wlds[d][row * WSTR + c4 * 2] =
            make_uint2(packh2(f.x, f.y), packh2(f.z, f.w));
    }
    // wave7 register state: c for both dirs, prefetched G for both dirs
    float cf = 0.f, cb = 0.f;
    float gFi = 0.f, gFf = 0.f, gFg = 0.f, gFo = 0.f;
    float gBi = 0.f, gBf = 0.f, gBg = 0.f, gBo = 0.f;
    if (tid >= 448) {
        int L = tid - 448, r = L & 15;
        cf = c0l[blk * HB + r];
        cb = c0l[H + blk * HB + r];
        const float* gp0 = G + blk * HB + r;                         // fwd t=0
        gFi = gp0[0]; gFf = gp0[H]; gFg = gp0[2 * H]; gFo = gp0[3 * H];
        const float* gp1 = G + ((size_t)T + (T - 1)) * G4 + blk * HB + r; // bwd t=T-1
        gBi = gp1[0]; gBf = gp1[H]; gBg = gp1[2 * H]; gBo = gp1[3 * H];
    } else if (tid < 8) {
        u64 v = sysload(sdF + blk * 8 + tid);            // own fwd, tag 0
        hshF[blk * 8 + tid] = (u32)(v >> 16);
    } else if (tid < 16) {
        u64 v = sysload(sdB + blk * 8 + (tid - 8));      // own bwd, tag 0
        hshB[blk * 8 + (tid - 8)] = (u32)(v >> 16);
    } else if (tid >= 256 && tid < 448) {
        // prologue poll: foreign fwd tag 0 (needed by phase-0 matvec)
        int f = tid - 256;
        int widx = f + (f >= blk * 8 ? 8 : 0);
        u64* src = sdF + widx;
        u64 v = sysload(src);
        int spins = 0;
        while ((unsigned)(v & 0xFFFFULL) != 0u) {
            if (++spins > 16384) {
                v = __hip_atomic_fetch_add(src, 0ULL, __ATOMIC_RELAXED,
                                           __HIP_MEMORY_SCOPE_AGENT);
            } else {
                v = sysload(src);
            }
        }
        hshF[widx] = (u32)(v >> 16);
    }
    __syncthreads();

#pragma clang loop unroll(disable)
    for (int p = 0; p <= 2 * T; ++p) {
        if (tid < 256) {
            if (p < 2 * T) {
                // worker: matvec dir d=p&1, gate row = tid>>2, slice = tid&3
                const int d = p & 1;
                const int row = tid >> 2, sl = tid & 3;
                const u32* wp = &wlds[d][row * WSTR + sl * 50];
                const u32* hp = (d ? hshB : hshF) + sl * 50;
                float a0 = 0.f, a1 = 0.f, a2 = 0.f, a3 = 0.f;
#pragma unroll
                for (int i = 0; i < 12; ++i) {
                    uint2 wv0 = *(const uint2*)&wp[4 * i];
                    uint2 hv0 = *(const uint2*)&hp[4 * i];
                    uint2 wv1 = *(const uint2*)&wp[4 * i + 2];
                    uint2 hv1 = *(const uint2*)&hp[4 * i + 2];
                    a0 = dot2u(wv0.x, hv0.x, a0);
                    a1 = dot2u(wv0.y, hv0.y, a1);
                    a2 = dot2u(wv1.x, hv1.x, a2);
                    a3 = dot2u(wv1.y, hv1.y, a3);
                }
                {
                    uint2 wv = *(const uint2*)&wp[48];
                    uint2 hv = *(const uint2*)&hp[48];
                    a0 = dot2u(wv.x, hv.x, a0);
                    a1 = dot2u(wv.y, hv.y, a1);
                }
                float a = (a0 + a1) + (a2 + a3);
                a += __shfl_xor(a, 1);    // combine the 4 k-slices
                a += __shfl_xor(a, 2);
                if (sl == 0) gsum[d][row] = a;
            }
        } else if (tid < 448) {
            // poller: words needed by workers at phase p+1
            int dd, tg;
            if (p & 1) { dd = 0; tg = ((p - 1) >> 1) + 1; }   // fwd tag s+1
            else       { dd = 1; tg = p >> 1; }               // bwd tag s
            if (tg < T) {
                int f = tid - 256;
                int widx = f + (f >= blk * 8 ? 8 : 0);
                u64* src = (dd ? sdB : sdF) + (size_t)(tg & 1) * NPAIR + widx;
                u64 v = sysload(src);
                int spins = 0;
                while ((unsigned)(v & 0xFFFFULL) != (unsigned)tg) {
                    if (++spins > 16384) {
                        v = __hip_atomic_fetch_add(src, 0ULL, __ATOMIC_RELAXED,
                                                   __HIP_MEMORY_SCOPE_AGENT);
                    } else {
                        v = sysload(src);
                    }
                }
                (dd ? hshB : hshF)[widx] = (u32)(v >> 16);
            }
        } else if (p >= 1) {
            // wave7: gate math + publish for the dir whose matvec ran at p-1
            const int L = tid - 448, r = L & 15;
            const int d = (p & 1) ? 0 : 1;
            const int s = (p & 1) ? ((p - 1) >> 1) : ((p - 2) >> 1);
            float iv, fv, gv, ov, c;
            if (d == 0) { iv = gFi; fv = gFf; gv = gFg; ov = gFo; c = cf; }
            else        { iv = gBi; fv = gBf; gv = gBg; ov = gBo; c = cb; }
            iv += gsum[d][r];
            fv += gsum[d][16 + r];
            gv += gsum[d][32 + r];
            ov += gsum[d][48 + r];
            float cn = sigf(fv) * c + sigf(iv) * tanhf_fast(gv);
            if (d == 0) cf = cn; else cb = cn;
            float hn = sigf(ov) * tanhf_fast(cn);
            u32 hb = (u32)f16bits((f16)hn);
            u32 lo = __shfl(hb, (2 * L) & 63);
            u32 hi = __shfl(hb, (2 * L + 1) & 63);
            if (L < 8) {
                u32 pk = (lo & 0xFFFFu) | (hi << 16);
                (d ? hshB : hshF)[blk * 8 + L] = pk;   // own slice, LDS fast-path
                sysstore((d ? sdB : sdF) + (size_t)((s + 1) & 1) * NPAIR + blk * 8 + L,
                         (u64)(unsigned)(s + 1) | ((u64)pk << 16));
            }
            const int tt = d ? (T - 1 - s) : s;
            if (L < 16)
                xout[(size_t)tt * (2 * H) + d * H + blk * HB + L] = hn;
            // prefetch G for this dir's NEXT gate (used at phase p+2)
            int sn = (s + 1 < T) ? (s + 1) : s;
            int ttn = d ? (T - 1 - sn) : sn;
            const float* gp = G + ((size_t)d * T + ttn) * G4 + blk * HB + r;
            if (d == 0) { gFi = gp[0]; gFf = gp[H]; gFg = gp[2 * H]; gFo = gp[3 * H]; }
            else        { gBi = gp[0]; gBf = gp[H]; gBg = gp[2 * H]; gBo = gp[3 * H]; }
        }
        __syncthreads();   // single barrier per phase
    }
}

// ---------- fused pairwise scorer ----------
__global__ __launch_bounds__(256) void scores_k(
    const float* __restrict__ pi, const float* __restrict__ pj,
    const float* __restrict__ w2, const float* __restrict__ b2p,
    float* __restrict__ out) {
    __shared__ float Ps[16][401];
    __shared__ float Qs[16][401];
    __shared__ float w2s[400];
    const int tid = threadIdx.x;
    const int i0 = blockIdx.y * 16, j0 = blockIdx.x * 16;
    for (int r = 0; r < 16; r++) {
        for (int k = tid; k < MLP_H; k += 256) {
            Ps[r][k] = pi[(size_t)(i0 + r) * MLP_H + k];
            Qs[r][k] = pj[(size_t)(j0 + r) * MLP_H + k];
        }
    }
    for (int k = tid; k < MLP_H; k += 256) w2s[k] = w2[k];
    __syncthreads();
    const int ti = tid >> 4, tj = tid & 15;
    float acc = 0.f;
#pragma unroll 4
    for (int k = 0; k < MLP_H; k++) {
        float x = Ps[ti][k] + Qs[tj][k];
        acc = fmaf(w2s[k], tanhf_fast(x), acc);
    }
    const int i = i0 + ti, j = j0 + tj;
    out[(size_t)i * T + j] = (i == j) ? 0.f : (acc + b2p[0]);
}

extern "C" void kernel_launch(void* const* d_in, const int* in_sizes, int n_in,
                              void* d_out, int out_size, void* d_ws, size_t ws_size,
                              hipStream_t stream) {
    const int*   words = (const int*)d_in[0];
    const int*   tags  = (const int*)d_in[1];
    const float* wemb  = (const float*)d_in[2];
    const float* temb  = (const float*)d_in[3];
    const float* Wih0  = (const float*)d_in[4];
    const float* Whh0  = (const float*)d_in[5];
    const float* bih0  = (const float*)d_in[6];
    const float* bhh0  = (const float*)d_in[7];
    const float* Wih1  = (const float*)d_in[8];
    const float* Whh1  = (const float*)d_in[9];
    const float* bih1  = (const float*)d_in[10];
    const float* bhh1  = (const float*)d_in[11];
    const float* W1    = (const float*)d_in[12];
    const float* b1    = (const float*)d_in[13];
    const float* W2    = (const float*)d_in[14];
    const float* b2    = (const float*)d_in[15];
    const float* h0    = (const float*)d_in[16];
    const float* c0    = (const float*)d_in[17];
    float* out = (float*)d_out;

    float* W = (float*)d_ws;
    float* x0   = W;                 // 256*400 (dead after layer-0 GEMMs)
    float* x1   = W + 102400;        // 256*800
    float* hvec = W + 307200;        // 256*800
    float* Gb   = W + 512000;        // 2*256*1600 (reused for both layers)
    float* pi   = W + 1331200;       // 256*400
    float* pj   = W + 1433600;       // 256*400
    // word arrays overlap x0's region (x0 dead before lstm_init5 runs)
    u64* slotsA = (u64*)W;                               // 800 u64
    u64* slotsB = (u64*)(W + 2048);                      // 800 u64

    // 1. embedding gather
    gather_k<<<T, 128, 0, stream>>>(words, tags, wemb, temb, x0);

    // 2. layer-0 gate inputs
    for (int d = 0; d < 2; d++) {
        gemm_tn<<<dim3(4, 25), 256, 0, stream>>>(
            x0, H, Wih0 + (size_t)d * G4 * H, H, 0,
            bih0 + d * G4, bhh0 + d * G4,
            Gb + (size_t)d * T * G4, G4, G4, H);
    }
    // 3. init tagged words (x0 now dead), then LSTM layer 0
    lstm_init5<<<1, 256, 0, stream>>>(h0, slotsA, slotsB);
    lstm_layer_dual<<<NBLK, 512, 0, stream>>>(Gb, Whh0, c0, x1, slotsA);

    // 4. layer-1 gate inputs (K=800)
    for (int d = 0; d < 2; d++) {
        gemm_tn<<<dim3(4, 25), 256, 0, stream>>>(
            x1, 2 * H, Wih1 + (size_t)d * G4 * (2 * H), 2 * H, 0,
            bih1 + d * G4, bhh1 + d * G4,
            Gb + (size_t)d * T * G4, G4, G4, 2 * H);
    }
    // 5. LSTM layer 1
    lstm_layer_dual<<<NBLK, 512, 0, stream>>>(Gb, Whh1, c0 + 2 * H, hvec, slotsB);

    // 6. pi = hvec @ W1a.T + b1 ; pj = hvec @ W1b.T
    gemm_tn<<<dim3(4, 7), 256, 0, stream>>>(
        hvec, 2 * H, W1, G4, 0, b1, nullptr, pi, MLP_H, MLP_H, 2 * H);
    gemm_tn<<<dim3(4, 7), 256, 0, stream>>>(
        hvec, 2 * H, W1, G4, 2 * H, nullptr, nullptr, pj, MLP_H, MLP_H, 2 * H);

    // 7. fused pairwise scores
    scores_k<<<dim3(16, 16), 256, 0, stream>>>(pi, pj, W2, b2, out);
}

// Round 7
// 1697.612 us; speedup vs baseline: 1.1156x; 1.1156x over previous
//
#include <hip/hip_runtime.h>
#include <hip/hip_bf16.h>

#define T 256
#define H 400
#define G4 1600   // 4*H
#define WD 300
#define TD 100
#define MLP_H 400
#define NBLK 25         // blocks total; each handles BOTH directions
#define HB 16           // h-rows per block (per direction)
#define GR 64           // gate-rows per block per direction (4*HB)
#define WSTR 202        // LDS weight row stride in u32 (bank-conflict pad)
#define NPAIR 200       // 400 h values -> 200 tagged 64-bit words per dir

typedef _Float16 f16;
typedef _Float16 half2t __attribute__((ext_vector_type(2)));
typedef unsigned long long u64;
typedef unsigned int u32;

// ---------- math helpers ----------
__device__ __forceinline__ float fexp(float x) {
    return __builtin_amdgcn_exp2f(x * 1.4426950408889634f);
}
__device__ __forceinline__ float sigf(float x) {
    return __builtin_amdgcn_rcpf(1.0f + fexp(-x));
}
__device__ __forceinline__ float tanhf_fast(float x) {
    return 1.0f - 2.0f * __builtin_amdgcn_rcpf(1.0f + fexp(2.0f * x));
}
__device__ __forceinline__ unsigned short f16bits(f16 x) {
    union { f16 h; unsigned short u; } v; v.h = x; return v.u;
}
__device__ __forceinline__ u32 packh2(float a, float b) {
    half2t hv; hv.x = (_Float16)a; hv.y = (_Float16)b;
    return __builtin_bit_cast(u32, hv);
}

#if __has_builtin(__builtin_amdgcn_fdot2)
__device__ __forceinline__ float dot2u(u32 a, u32 b, float c) {
    return __builtin_amdgcn_fdot2(__builtin_bit_cast(half2t, a),
                                  __builtin_bit_cast(half2t, b), c, false);
}
#else
__device__ __forceinline__ float dot2u(u32 a, u32 b, float c) {
    half2t x = __builtin_bit_cast(half2t, a), y = __builtin_bit_cast(half2t, b);
    return fmaf((float)x.y, (float)y.y, fmaf((float)x.x, (float)y.x, c));
}
#endif

// system-scope (sc0 sc1) plain ops: bypass L1/L2, serviced at the IC --
// coherent across XCDs without RMWs or fences. (R0-proven transport.)
__device__ __forceinline__ u64 sysload(const u64* p) {
    return __hip_atomic_load(p, __ATOMIC_RELAXED, __HIP_MEMORY_SCOPE_SYSTEM);
}
__device__ __forceinline__ void sysstore(u64* p, u64 v) {
    __hip_atomic_store(p, v, __ATOMIC_RELAXED, __HIP_MEMORY_SCOPE_SYSTEM);
}

// ---------- embedding gather ----------
__global__ void gather_k(const int* __restrict__ words, const int* __restrict__ tags,
                         const float* __restrict__ wemb, const float* __restrict__ temb,
                         float* __restrict__ x0) {
    int t = blockIdx.x;
    int w = words[t], g = tags[t];
    for (int c = threadIdx.x; c < H; c += 128) {
        float v = (c < WD) ? wemb[w * WD + c] : temb[g * TD + (c - WD)];
        x0[t * H + c] = v;
    }
}

// ---------- generic GEMM: out[t][r] = sum_k X[t*ldx+k]*W[r*ldw+wofs+k] + bias1[r]+bias2[r]
__global__ __launch_bounds__(256) void gemm_tn(
    const float* __restrict__ X, int ldx,
    const float* __restrict__ Wt, int ldw, int wofs,
    const float* __restrict__ bias1, const float* __restrict__ bias2,
    float* __restrict__ out, int ldo, int Rt, int K) {
    __shared__ float Xs[64][17];
    __shared__ float Ws[64][17];
    const int tid = threadIdx.x;
    const int t0 = blockIdx.x * 64, r0 = blockIdx.y * 64;
    const int lr = tid >> 2, kq = (tid & 3) * 4;
    const int ti = tid >> 4, rj = tid & 15;
    float acc[4][4] = {};
    for (int k0 = 0; k0 < K; k0 += 16) {
        float4 xv = *(const float4*)(X + (size_t)(t0 + lr) * ldx + k0 + kq);
        Xs[lr][kq + 0] = xv.x; Xs[lr][kq + 1] = xv.y;
        Xs[lr][kq + 2] = xv.z; Xs[lr][kq + 3] = xv.w;
        int r = r0 + lr;
        float4 wv = make_float4(0.f, 0.f, 0.f, 0.f);
        if (r < Rt) wv = *(const float4*)(Wt + (size_t)r * ldw + wofs + k0 + kq);
        Ws[lr][kq + 0] = wv.x; Ws[lr][kq + 1] = wv.y;
        Ws[lr][kq + 2] = wv.z; Ws[lr][kq + 3] = wv.w;
        __syncthreads();
#pragma unroll
        for (int k = 0; k < 16; k++) {
            float xr[4], wr[4];
#pragma unroll
            for (int m = 0; m < 4; m++) xr[m] = Xs[ti * 4 + m][k];
#pragma unroll
            for (int n = 0; n < 4; n++) wr[n] = Ws[rj * 4 + n][k];
#pragma unroll
            for (int m = 0; m < 4; m++)
#pragma unroll
                for (int n = 0; n < 4; n++)
                    acc[m][n] = fmaf(xr[m], wr[n], acc[m][n]);
        }
        __syncthreads();
    }
    int rq = r0 + rj * 4;
    if (rq < Rt) {
        float b[4];
#pragma unroll
        for (int n = 0; n < 4; n++) {
            int r = rq + n;
            b[n] = (bias1 ? bias1[r] : 0.f) + (bias2 ? bias2[r] : 0.f);
        }
#pragma unroll
        for (int m = 0; m < 4; m++) {
            int t = t0 + ti * 4 + m;
            float4 o;
            o.x = acc[m][0] + b[0]; o.y = acc[m][1] + b[1];
            o.z = acc[m][2] + b[2]; o.w = acc[m][3] + b[3];
            *(float4*)(out + (size_t)t * ldo + rq) = o;
        }
    }
}

// ---------- init: tagged words, contiguous [dir][parity][NPAIR] ----------
__global__ void lstm_init5(const float* __restrict__ h0, u64* sA, u64* sB) {
    int tid = threadIdx.x;
    const int TOT = 2 * 2 * NPAIR;
    for (int i = tid; i < TOT; i += 256) { sA[i] = 0xFFFFULL; sB[i] = 0xFFFFULL; }
    __syncthreads();
    for (int p = tid; p < 2 * NPAIR; p += 256) {
        int d = p / NPAIR, pr = p - d * NPAIR;
        size_t off = (size_t)(d * 2 + 0) * NPAIR + pr;   // parity 0, tag 0
        f16 a0 = (f16)h0[d * H + 2 * pr], b0 = (f16)h0[d * H + 2 * pr + 1];
        sA[off] = 0ULL | ((u64)f16bits(a0) << 16) | ((u64)f16bits(b0) << 32);
        f16 a1 = (f16)h0[2 * H + d * H + 2 * pr], b1 = (f16)h0[2 * H + d * H + 2 * pr + 1];
        sB[off] = 0ULL | ((u64)f16bits(a1) << 16) | ((u64)f16bits(b1) << 32);
    }
}

// ---------- persistent LSTM layer v15: single barrier + in-phase gates ----------
// grid = 25 blocks, 512 threads; each block owns h-rows [blk*16,+16) for BOTH
// directions (weights 101 KiB LDS). 2T phases, ONE __syncthreads each.
// Phase p (d=p&1, s=p>>1):
//   workers (tid<256): matvec dir d over hsh{F,B}[s&1] -> gsum[d]; then
//     s_waitcnt lgkmcnt(0); lane0-of-wave writes wflag[w]=p (handshake).
//   pollers (256..447): fetch the words workers need at phase p+1 -- these
//     were published during phase p-1 (full phase of slack, IC RT hidden).
//   wave7 (448..511): swap in prefetched G(d,s), issue G(d,s+1) prefetch,
//     SPIN on wflag (LDS, ~60cy), gate math, publish h_{s+1} (IC store +
//     own words into hsh[(s+1)&1]) -- publish lands MID-PHASE, giving next
//     phase's pollers (other blocks) their full-phase slack.
// Hazards: hsh double-buffered by step parity (matvec reads [s&1]; wave7/
// pollers write [(s+1)&1], barrier-separated); gsum[d] written+read in
// phase p, rewritten p+2; wflag monotonic (=p), init ~0. Skew <=1 phase by
// the R0 induction; slot-parity overwrite needs 2-step skew -> safe.
// Liveness: wave7 waits only on own workers; workers only on last-phase
// installs; pollers only on other blocks' wave7 -- acyclic per phase.
__global__ __launch_bounds__(512, 1) void lstm_layer_dual(
    const float* __restrict__ G,     // [2][T][G4] gate inputs, biases folded
    const float* __restrict__ Whh,   // [2][G4][H]
    const float* __restrict__ c0l,   // [2][H] this layer
    float* __restrict__ xout,        // [T][2H]
    u64* __restrict__ slots) {       // [2][2][NPAIR]
    const int blk = blockIdx.x;
    const int tid = threadIdx.x;
    u64* sdF = slots;
    u64* sdB = slots + 2 * NPAIR;

    __shared__ u32 wlds[2][GR * WSTR];           // 2 x 50.5 KiB = 101 KiB
    __shared__ __align__(16) u32 hshF[2][NPAIR]; // fwd h, step-parity dbuf
    __shared__ __align__(16) u32 hshB[2][NPAIR]; // bwd h
    __shared__ float gsum[2][GR];                // per-dir matvec sums
    __shared__ u32 wflag[4];                     // worker-wave handshake

    // ---- one-time: pack weights fp32 -> half2 into LDS (both dirs) ----
    for (int idx = tid; idx < 2 * GR * 100; idx += 512) {
        int d = idx / (GR * 100), rem = idx - d * (GR * 100);
        int row = rem / 100, c4 = rem - row * 100;
        int g = row >> 4, r = row & 15;
        const float4* src = (const float4*)(
            Whh + (size_t)d * G4 * H + (size_t)(g * H + blk * HB + r) * H);
        float4 f = src[c4];
        *(uint2*)&wlds[d][row * WSTR + c4 * 2] =
            make_uint2(packh2(f.x, f.y), packh2(f.z, f.w));
    }
    if (tid < 4) wflag[tid] = 0xFFFFFFFFu;

    // wave7 register state: c both dirs; prefetched-G pipeline regs
    float cf = 0.f, cb = 0.f;
    float gFi = 0.f, gFf = 0.f, gFg = 0.f, gFo = 0.f;
    float gBi = 0.f, gBf = 0.f, gBg = 0.f, gBo = 0.f;
    float nFi = 0.f, nFf = 0.f, nFg = 0.f, nFo = 0.f;
    float nBi = 0.f, nBf = 0.f, nBg = 0.f, nBo = 0.f;
    if (tid >= 448) {
        int L = tid - 448, r = L & 15;
        cf = c0l[blk * HB + r];
        cb = c0l[H + blk * HB + r];
        const float* gp0 = G + blk * HB + r;                              // fwd t=0
        nFi = gp0[0]; nFf = gp0[H]; nFg = gp0[2 * H]; nFo = gp0[3 * H];
        const float* gp1 = G + ((size_t)T + (T - 1)) * G4 + blk * HB + r; // bwd t=T-1
        nBi = gp1[0]; nBf = gp1[H]; nBg = gp1[2 * H]; nBo = gp1[3 * H];
    } else if (tid < 8) {
        u64 v = sysload(sdF + blk * 8 + tid);            // own fwd, tag 0
        hshF[0][blk * 8 + tid] = (u32)(v >> 16);
    } else if (tid < 16) {
        u64 v = sysload(sdB + blk * 8 + (tid - 8));      // own bwd, tag 0
        hshB[0][blk * 8 + (tid - 8)] = (u32)(v >> 16);
    } else if (tid >= 256 && tid < 448) {
        // prologue poll: foreign fwd tag 0 (needed by phase-0 matvec)
        int f = tid - 256;
        int widx = f + (f >= blk * 8 ? 8 : 0);
        u64* src = sdF + widx;
        u64 v = sysload(src);
        int spins = 0;
        while ((unsigned)(v & 0xFFFFULL) != 0u) {
            if (++spins > 16384) {
                v = __hip_atomic_fetch_add(src, 0ULL, __ATOMIC_RELAXED,
                                           __HIP_MEMORY_SCOPE_AGENT);
            } else {
                v = sysload(src);
            }
        }
        hshF[0][widx] = (u32)(v >> 16);
    }
    __syncthreads();

#pragma clang loop unroll(disable)
    for (int p = 0; p < 2 * T; ++p) {
        const int d = p & 1, s = p >> 1;
        if (tid < 256) {
            // worker: matvec dir d, gate row = tid>>2, slice = tid&3
            const int row = tid >> 2, sl = tid & 3;
            const u32* wp = &wlds[d][row * WSTR + sl * 50];
            const u32* hp = (d ? hshB[s & 1] : hshF[s & 1]) + sl * 50;
            float a0 = 0.f, a1 = 0.f, a2 = 0.f, a3 = 0.f;
#pragma unroll
            for (int i = 0; i < 12; ++i) {
                uint2 wv0 = *(const uint2*)&wp[4 * i];
                uint2 hv0 = *(const uint2*)&hp[4 * i];
                uint2 wv1 = *(const uint2*)&wp[4 * i + 2];
                uint2 hv1 = *(const uint2*)&hp[4 * i + 2];
                a0 = dot2u(wv0.x, hv0.x, a0);
                a1 = dot2u(wv0.y, hv0.y, a1);
                a2 = dot2u(wv1.x, hv1.x, a2);
                a3 = dot2u(wv1.y, hv1.y, a3);
            }
            {
                uint2 wv = *(const uint2*)&wp[48];
                uint2 hv = *(const uint2*)&hp[48];
                a0 = dot2u(wv.x, hv.x, a0);
                a1 = dot2u(wv.y, hv.y, a1);
            }
            float a = (a0 + a1) + (a2 + a3);
            a += __shfl_xor(a, 1);    // combine the 4 k-slices
            a += __shfl_xor(a, 2);
            if (sl == 0) gsum[d][row] = a;
            asm volatile("s_waitcnt lgkmcnt(0)" ::: "memory");
            if ((tid & 63) == 0) wflag[tid >> 6] = (u32)p;   // handshake
        } else if (tid < 448) {
            // poller: words needed by workers at phase p+1 (published @ p-1)
            const int d1 = (p + 1) & 1, s1 = (p + 1) >> 1;
            if (s1 < T) {
                int f = tid - 256;
                int widx = f + (f >= blk * 8 ? 8 : 0);
                u64* src = (d1 ? sdB : sdF) + (size_t)(s1 & 1) * NPAIR + widx;
                u64 v = sysload(src);
                int spins = 0;
                while ((unsigned)(v & 0xFFFFULL) != (unsigned)s1) {
                    if (++spins > 16384) {
                        v = __hip_atomic_fetch_add(src, 0ULL, __ATOMIC_RELAXED,
                                                   __HIP_MEMORY_SCOPE_AGENT);
                    } else {
                        v = sysload(src);
                    }
                }
                (d1 ? hshB[s1 & 1] : hshF[s1 & 1])[widx] = (u32)(v >> 16);
            }
        } else {
            // wave7: in-phase gates + publish for (d, s)
            const int L = tid - 448, r = L & 15;
            // swap in prefetched G(d,s); issue prefetch G(d,s+1) (used p+2)
            if (d == 0) { gFi = nFi; gFf = nFf; gFg = nFg; gFo = nFo; }
            else        { gBi = nBi; gBf = nBf; gBg = nBg; gBo = nBo; }
            {
                int sn = (s + 1 < T) ? (s + 1) : s;
                int ttn = d ? (T - 1 - sn) : sn;
                const float* gp = G + ((size_t)d * T + ttn) * G4 + blk * HB + r;
                if (d == 0) { nFi = gp[0]; nFf = gp[H]; nFg = gp[2 * H]; nFo = gp[3 * H]; }
                else        { nBi = gp[0]; nBf = gp[H]; nBg = gp[2 * H]; nBo = gp[3 * H]; }
            }
            // wait for workers' gsum (LDS handshake, ~60cy)
            {
                const volatile u32* vf = wflag;
                while (!((vf[0] == (u32)p) && (vf[1] == (u32)p) &&
                         (vf[2] == (u32)p) && (vf[3] == (u32)p))) {}
            }
            asm volatile("" ::: "memory");
            float iv, fv, gv, ov, c;
            if (d == 0) { iv = gFi; fv = gFf; gv = gFg; ov = gFo; c = cf; }
            else        { iv = gBi; fv = gBf; gv = gBg; ov = gBo; c = cb; }
            iv += gsum[d][r];
            fv += gsum[d][16 + r];
            gv += gsum[d][32 + r];
            ov += gsum[d][48 + r];
            float cn = sigf(fv) * c + sigf(iv) * tanhf_fast(gv);
            if (d == 0) cf = cn; else cb = cn;
            float hn = sigf(ov) * tanhf_fast(cn);
            u32 hb = (u32)f16bits((f16)hn);
            u32 lo = __shfl(hb, (2 * L) & 63);
            u32 hi = __shfl(hb, (2 * L + 1) & 63);
            if (L < 8) {
                u32 pk = (lo & 0xFFFFu) | (hi << 16);
                (d ? hshB[(s + 1) & 1] : hshF[(s + 1) & 1])[blk * 8 + L] = pk;
                sysstore((d ? sdB : sdF) + (size_t)((s + 1) & 1) * NPAIR + blk * 8 + L,
                         (u64)(unsigned)(s + 1) | ((u64)pk << 16));
            }
            const int tt = d ? (T - 1 - s) : s;
            if (L < 16)
                xout[(size_t)tt * (2 * H) + d * H + blk * HB + L] = hn;
        }
        __syncthreads();   // single barrier per phase
    }
}

// ---------- fused pairwise scorer ----------
__global__ __launch_bounds__(256) void scores_k(
    const float* __restrict__ pi, const float* __restrict__ pj,
    const float* __restrict__ w2, const float* __restrict__ b2p,
    float* __restrict__ out) {
    __shared__ float Ps[16][401];
    __shared__ float Qs[16][401];
    __shared__ float w2s[400];
    const int tid = threadIdx.x;
    const int i0 = blockIdx.y * 16, j0 = blockIdx.x * 16;
    for (int r = 0; r < 16; r++) {
        for (int k = tid; k < MLP_H; k += 256) {
            Ps[r][k] = pi[(size_t)(i0 + r) * MLP_H + k];
            Qs[r][k] = pj[(size_t)(j0 + r) * MLP_H + k];
        }
    }
    for (int k = tid; k < MLP_H; k += 256) w2s[k] = w2[k];
    __syncthreads();
    const int ti = tid >> 4, tj = tid & 15;
    float acc = 0.f;
#pragma unroll 4
    for (int k = 0; k < MLP_H; k++) {
        float x = Ps[ti][k] + Qs[tj][k];
        acc = fmaf(w2s[k], tanhf_fast(x), acc);
    }
    const int i = i0 + ti, j = j0 + tj;
    out[(size_t)i * T + j] = (i == j) ? 0.f : (acc + b2p[0]);
}

extern "C" void kernel_launch(void* const* d_in, const int* in_sizes, int n_in,
                              void* d_out, int out_size, void* d_ws, size_t ws_size,
                              hipStream_t stream) {
    const int*   words = (const int*)d_in[0];
    const int*   tags  = (const int*)d_in[1];
    const float* wemb  = (const float*)d_in[2];
    const float* temb  = (const float*)d_in[3];
    const float* Wih0  = (const float*)d_in[4];
    const float* Whh0  = (const float*)d_in[5];
    const float* bih0  = (const float*)d_in[6];
    const float* bhh0  = (const float*)d_in[7];
    const float* Wih1  = (const float*)d_in[8];
    const float* Whh1  = (const float*)d_in[9];
    const float* bih1  = (const float*)d_in[10];
    const float* bhh1  = (const float*)d_in[11];
    const float* W1    = (const float*)d_in[12];
    const float* b1    = (const float*)d_in[13];
    const float* W2    = (const float*)d_in[14];
    const float* b2    = (const float*)d_in[15];
    const float* h0    = (const float*)d_in[16];
    const float* c0    = (const float*)d_in[17];
    float* out = (float*)d_out;

    float* W = (float*)d_ws;
    float* x0   = W;                 // 256*400 (dead after layer-0 GEMMs)
    float* x1   = W + 102400;        // 256*800
    float* hvec = W + 307200;        // 256*800
    float* Gb   = W + 512000;        // 2*256*1600 (reused for both layers)
    float* pi   = W + 1331200;       // 256*400
    float* pj   = W + 1433600;       // 256*400
    // word arrays overlap x0's region (x0 dead before lstm_init5 runs)
    u64* slotsA = (u64*)W;                               // 800 u64
    u64* slotsB = (u64*)(W + 2048);                      // 800 u64

    // 1. embedding gather
    gather_k<<<T, 128, 0, stream>>>(words, tags, wemb, temb, x0);

    // 2. layer-0 gate inputs
    for (int d = 0; d < 2; d++) {
        gemm_tn<<<dim3(4, 25), 256, 0, stream>>>(
            x0, H, Wih0 + (size_t)d * G4 * H, H, 0,
            bih0 + d * G4, bhh0 + d * G4,
            Gb + (size_t)d * T * G4, G4, G4, H);
    }
    // 3. init tagged words (x0 now dead), then LSTM layer 0
    lstm_init5<<<1, 256, 0, stream>>>(h0, slotsA, slotsB);
    lstm_layer_dual<<<NBLK, 512, 0, stream>>>(Gb, Whh0, c0, x1, slotsA);

    // 4. layer-1 gate inputs (K=800)
    for (int d = 0; d < 2; d++) {
        gemm_tn<<<dim3(4, 25), 256, 0, stream>>>(
            x1, 2 * H, Wih1 + (size_t)d * G4 * (2 * H), 2 * H, 0,
            bih1 + d * G4, bhh1 + d * G4,
            Gb + (size_t)d * T * G4, G4, G4, 2 * H);
    }
    // 5. LSTM layer 1
    lstm_layer_dual<<<NBLK, 512, 0, stream>>>(Gb, Whh1, c0 + 2 * H, hvec, slotsB);

    // 6. pi = hvec @ W1a.T + b1 ; pj = hvec @ W1b.T
    gemm_tn<<<dim3(4, 7), 256, 0, stream>>>(
        hvec, 2 * H, W1, G4, 0, b1, nullptr, pi, MLP_H, MLP_H, 2 * H);
    gemm_tn<<<dim3(4, 7), 256, 0, stream>>>(
        hvec, 2 * H, W1, G4, 2 * H, nullptr, nullptr, pj, MLP_H, MLP_H, 2 * H);

    // 7. fused pairwise scores
    scores_k<<<dim3(16, 16), 256, 0, stream>>>(pi, pj, W2, b2, out);
}

// Round 8
// 1320.073 us; speedup vs baseline: 1.4346x; 1.2860x over previous
//
#include <hip/hip_runtime.h>
#include <hip/hip_bf16.h>

#define T 256
#define H 400
#define G4 1600   // 4*H
#define WD 300
#define TD 100
#define MLP_H 400
#define NBLK_D 25       // blocks per direction (50 total)
#define HB 16           // h-rows per block
#define GR 64           // gate-rows per block (4*HB)
#define WSTR 202        // LDS weight row stride in u32 (bank-conflict pad)
#define NPAIR 200       // 400 h values -> 200 tagged 64-bit words

typedef _Float16 f16;
typedef _Float16 half2t __attribute__((ext_vector_type(2)));
typedef unsigned long long u64;
typedef unsigned int u32;

// ---------- math helpers ----------
__device__ __forceinline__ float fexp(float x) {
    return __builtin_amdgcn_exp2f(x * 1.4426950408889634f);
}
__device__ __forceinline__ float sigf(float x) {
    return __builtin_amdgcn_rcpf(1.0f + fexp(-x));
}
__device__ __forceinline__ float tanhf_fast(float x) {
    return 1.0f - 2.0f * __builtin_amdgcn_rcpf(1.0f + fexp(2.0f * x));
}
__device__ __forceinline__ unsigned short f16bits(f16 x) {
    union { f16 h; unsigned short u; } v; v.h = x; return v.u;
}
__device__ __forceinline__ u32 packh2(float a, float b) {
    half2t hv; hv.x = (_Float16)a; hv.y = (_Float16)b;
    return __builtin_bit_cast(u32, hv);
}

#if __has_builtin(__builtin_amdgcn_fdot2)
__device__ __forceinline__ float dot2u(u32 a, u32 b, float c) {
    return __builtin_amdgcn_fdot2(__builtin_bit_cast(half2t, a),
                                  __builtin_bit_cast(half2t, b), c, false);
}
#else
__device__ __forceinline__ float dot2u(u32 a, u32 b, float c) {
    half2t x = __builtin_bit_cast(half2t, a), y = __builtin_bit_cast(half2t, b);
    return fmaf((float)x.y, (float)y.y, fmaf((float)x.x, (float)y.x, c));
}
#endif

// system-scope (sc0 sc1) plain ops: bypass L1/L2, serviced at the IC --
// coherent across XCDs without RMWs or fences.
__device__ __forceinline__ u64 sysload(const u64* p) {
    return __hip_atomic_load(p, __ATOMIC_RELAXED, __HIP_MEMORY_SCOPE_SYSTEM);
}
__device__ __forceinline__ void sysstore(u64* p, u64 v) {
    __hip_atomic_store(p, v, __ATOMIC_RELAXED, __HIP_MEMORY_SCOPE_SYSTEM);
}

// ---------- embedding gather ----------
__global__ void gather_k(const int* __restrict__ words, const int* __restrict__ tags,
                         const float* __restrict__ wemb, const float* __restrict__ temb,
                         float* __restrict__ x0) {
    int t = blockIdx.x;
    int w = words[t], g = tags[t];
    for (int c = threadIdx.x; c < H; c += 128) {
        float v = (c < WD) ? wemb[w * WD + c] : temb[g * TD + (c - WD)];
        x0[t * H + c] = v;
    }
}

// ---------- z-batched GEMM: two independent problems (e.g. fwd/bwd dir) in
// one launch via blockIdx.z -- runs them CONCURRENTLY instead of as two
// sequential stream launches at 39% CU utilization each.
// out[z][t][r] = sum_k X[t*ldx+k] * Wt[z*wz + r*ldw + wofs0+z*wstep + k]
//               + bias1[z*b1zs + r] (if b1mask>>z&1) + bias2[...]
__global__ __launch_bounds__(256) void gemm_tnz(
    const float* __restrict__ X, int ldx,
    const float* __restrict__ Wt, long wz, int ldw, int wofs0, int wstep,
    const float* __restrict__ bias1, int b1zs, int b1mask,
    const float* __restrict__ bias2, int b2zs, int b2mask,
    float* __restrict__ out, int ldo, long ozs, int Rt, int K) {
    __shared__ float Xs[64][17];
    __shared__ float Ws[64][17];
    const int tid = threadIdx.x;
    const int z = blockIdx.z;
    const float* Wtz = Wt + (size_t)z * wz;
    const int wofs = wofs0 + z * wstep;
    const float* b1 = (bias1 && ((b1mask >> z) & 1)) ? bias1 + (size_t)z * b1zs : nullptr;
    const float* b2 = (bias2 && ((b2mask >> z) & 1)) ? bias2 + (size_t)z * b2zs : nullptr;
    float* outz = out + (size_t)z * ozs;
    const int t0 = blockIdx.x * 64, r0 = blockIdx.y * 64;
    const int lr = tid >> 2, kq = (tid & 3) * 4;
    const int ti = tid >> 4, rj = tid & 15;
    float acc[4][4] = {};
    for (int k0 = 0; k0 < K; k0 += 16) {
        float4 xv = *(const float4*)(X + (size_t)(t0 + lr) * ldx + k0 + kq);
        Xs[lr][kq + 0] = xv.x; Xs[lr][kq + 1] = xv.y;
        Xs[lr][kq + 2] = xv.z; Xs[lr][kq + 3] = xv.w;
        int r = r0 + lr;
        float4 wv = make_float4(0.f, 0.f, 0.f, 0.f);
        if (r < Rt) wv = *(const float4*)(Wtz + (size_t)r * ldw + wofs + k0 + kq);
        Ws[lr][kq + 0] = wv.x; Ws[lr][kq + 1] = wv.y;
        Ws[lr][kq + 2] = wv.z; Ws[lr][kq + 3] = wv.w;
        __syncthreads();
#pragma unroll
        for (int k = 0; k < 16; k++) {
            float xr[4], wr[4];
#pragma unroll
            for (int m = 0; m < 4; m++) xr[m] = Xs[ti * 4 + m][k];
#pragma unroll
            for (int n = 0; n < 4; n++) wr[n] = Ws[rj * 4 + n][k];
#pragma unroll
            for (int m = 0; m < 4; m++)
#pragma unroll
                for (int n = 0; n < 4; n++)
                    acc[m][n] = fmaf(xr[m], wr[n], acc[m][n]);
        }
        __syncthreads();
    }
    int rq = r0 + rj * 4;
    if (rq < Rt) {
        float b[4];
#pragma unroll
        for (int n = 0; n < 4; n++) {
            int r = rq + n;
            b[n] = (b1 ? b1[r] : 0.f) + (b2 ? b2[r] : 0.f);
        }
#pragma unroll
        for (int m = 0; m < 4; m++) {
            int t = t0 + ti * 4 + m;
            float4 o;
            o.x = acc[m][0] + b[0]; o.y = acc[m][1] + b[1];
            o.z = acc[m][2] + b[2]; o.w = acc[m][3] + b[3];
            *(float4*)(outz + (size_t)t * ldo + rq) = o;
        }
    }
}

// ---------- init: tagged words, contiguous [dir][parity][NPAIR] ----------
__global__ void lstm_init5(const float* __restrict__ h0, u64* sA, u64* sB) {
    int tid = threadIdx.x;
    const int TOT = 2 * 2 * NPAIR;
    for (int i = tid; i < TOT; i += 256) { sA[i] = 0xFFFFULL; sB[i] = 0xFFFFULL; }
    __syncthreads();
    for (int p = tid; p < 2 * NPAIR; p += 256) {
        int d = p / NPAIR, pr = p - d * NPAIR;
        size_t off = (size_t)(d * 2 + 0) * NPAIR + pr;   // parity 0, tag 0
        f16 a0 = (f16)h0[d * H + 2 * pr], b0 = (f16)h0[d * H + 2 * pr + 1];
        sA[off] = 0ULL | ((u64)f16bits(a0) << 16) | ((u64)f16bits(b0) << 32);
        f16 a1 = (f16)h0[2 * H + d * H + 2 * pr], b1 = (f16)h0[2 * H + d * H + 2 * pr + 1];
        sB[off] = 0ULL | ((u64)f16bits(a1) << 16) | ((u64)f16bits(b1) << 32);
    }
}

// ---------- persistent LSTM layer v8 (R0-proven, best known: 508us/layer) ----------
// grid = 50 blocks (dir = b/25, blk = b%25), 512 threads. Block owns h rows
// [blk*16,+16) = 64 gate-rows. Weights live in LDS (50.5 KiB, loaded once).
// tid<256: workers, 4 per gate-row; tid in [256,448): pollers for the 192
// foreign tagged words (IC-scope sc0/sc1 scheme); tid>=448: G stagers.
// Wave 0 does gate math + publish via intra-wave shuffles. 2 barriers/step.
__global__ __launch_bounds__(512, 1) void lstm_layer8(
    const float* __restrict__ G,     // [2][T][G4] gate inputs, biases folded
    const float* __restrict__ Whh,   // [2][G4][H]
    const float* __restrict__ c0l,   // [2][H] this layer
    float* __restrict__ xout,        // [T][2H]
    u64* __restrict__ slots) {       // [2][2][NPAIR]
    const int role = blockIdx.x;
    const int dir = role / NBLK_D, blk = role - dir * NBLK_D;
    const int tid = threadIdx.x;
    const float* Wd = Whh + (size_t)dir * G4 * H;
    const float* Gd = G + (size_t)dir * T * G4;
    u64* sd = slots + (size_t)dir * 2 * NPAIR;

    __shared__ u32 wlds[GR * WSTR];            // 64 rows x 202 u32 = 50.5 KiB
    __shared__ __align__(16) u32 hsh[NPAIR];   // h_s as 200 packed half2
    __shared__ float gsum[GR];                 // per-gate-row matvec sums
    __shared__ float gsh[2][GR];               // staged G, double-buffered

    // ---- one-time: pack weights fp32 -> half2 into LDS ----
    for (int idx = tid; idx < GR * 100; idx += 512) {
        int row = idx / 100, c4 = idx - row * 100;
        int g = row >> 4, r = row & 15;
        const float4* src = (const float4*)(Wd + (size_t)(g * H + blk * HB + r) * H);
        float4 f = src[c4];
        *(uint2*)&wlds[row * WSTR + c4 * 2] =
            make_uint2(packh2(f.x, f.y), packh2(f.z, f.w));
    }
    // pre-stage G(0); own h0 words into LDS
    if (tid >= 448) {
        int i = tid - 448, gg = i >> 4, rr = i & 15;
        int tt0 = dir ? (T - 1) : 0;
        gsh[0][i] = Gd[(size_t)tt0 * G4 + gg * H + blk * HB + rr];
    } else if (tid < 8) {
        u64 v = sysload(sd + blk * 8 + tid);       // parity 0, tag 0
        hsh[blk * 8 + tid] = (u32)(v >> 16);
    }
    float c = (tid < 64) ? c0l[dir * H + blk * HB + (tid & 15)] : 0.f;
    __syncthreads();

#pragma clang loop unroll(disable)
    for (int s = 0; s < T; ++s) {
        if (tid >= 256 && tid < 448) {
            // poller: one foreign word (parity s&1, tag s)
            int f = tid - 256;
            int widx = f + (f >= blk * 8 ? 8 : 0);
            u64* src = sd + (size_t)(s & 1) * NPAIR + widx;
            u64 v = sysload(src);
            int spins = 0;
            while ((unsigned)(v & 0xFFFFULL) != (unsigned)s) {
                if (++spins > 16384) {
                    v = __hip_atomic_fetch_add(src, 0ULL, __ATOMIC_RELAXED,
                                               __HIP_MEMORY_SCOPE_AGENT);
                } else {
                    v = sysload(src);
                }
            }
            hsh[widx] = (u32)(v >> 16);
        } else if (tid >= 448) {
            // stager: G(s+1) into the other parity half
            int sn = (s + 1 < T) ? (s + 1) : s;
            int tt = dir ? (T - 1 - sn) : sn;
            int i = tid - 448, gg = i >> 4, rr = i & 15;
            gsh[(s + 1) & 1][i] = Gd[(size_t)tt * G4 + gg * H + blk * HB + rr];
        }
        __syncthreads();   // (A) h_s complete in LDS

        if (tid < 256) {
            const int row = tid >> 2, sl = tid & 3;
            const u32* wp = &wlds[row * WSTR + sl * 50];
            const u32* hp = &hsh[sl * 50];
            float a0 = 0.f, a1 = 0.f, a2 = 0.f, a3 = 0.f;
#pragma unroll
            for (int i = 0; i < 12; ++i) {
                uint2 wv0 = *(const uint2*)&wp[4 * i];
                uint2 hv0 = *(const uint2*)&hp[4 * i];
                uint2 wv1 = *(const uint2*)&wp[4 * i + 2];
                uint2 hv1 = *(const uint2*)&hp[4 * i + 2];
                a0 = dot2u(wv0.x, hv0.x, a0);
                a1 = dot2u(wv0.y, hv0.y, a1);
                a2 = dot2u(wv1.x, hv1.x, a2);
                a3 = dot2u(wv1.y, hv1.y, a3);
            }
            {
                uint2 wv = *(const uint2*)&wp[48];
                uint2 hv = *(const uint2*)&hp[48];
                a0 = dot2u(wv.x, hv.x, a0);
                a1 = dot2u(wv.y, hv.y, a1);
            }
            float a = (a0 + a1) + (a2 + a3);
            a += __shfl_xor(a, 1);    // combine the 4 k-slices (adjacent lanes)
            a += __shfl_xor(a, 2);
            if (sl == 0) gsum[row] = a;
        }
        __syncthreads();   // (B) sums ready

        if (tid < 64) {    // wave 0: gate math + publish, intra-wave only
            const int r = tid & 15;
            const float* gc = gsh[s & 1];
            float iv = gsum[r]      + gc[r];
            float fv = gsum[16 + r] + gc[16 + r];
            float gv = gsum[32 + r] + gc[32 + r];
            float ov = gsum[48 + r] + gc[48 + r];
            float cn = sigf(fv) * c + sigf(iv) * tanhf_fast(gv);
            c = cn;
            float hn = sigf(ov) * tanhf_fast(cn);
            u32 hb = (u32)f16bits((f16)hn);
            u32 lo = __shfl(hb, (2 * tid) & 63);
            u32 hi = __shfl(hb, (2 * tid + 1) & 63);
            if (tid < 8) {
                u32 pk = (lo & 0xFFFFu) | (hi << 16);
                hsh[blk * 8 + tid] = pk;   // own slice of h_{s+1}, LDS fast-path
                sysstore(sd + (size_t)((s + 1) & 1) * NPAIR + blk * 8 + tid,
                         (u64)(unsigned)(s + 1) | ((u64)pk << 16));
            }
            const int tt = dir ? (T - 1 - s) : s;
            if (tid < 16)
                xout[(size_t)tt * (2 * H) + dir * H + blk * HB + tid] = hn;
        }
    }
}

// ---------- fused pairwise scorer ----------
__global__ __launch_bounds__(256) void scores_k(
    const float* __restrict__ pi, const float* __restrict__ pj,
    const float* __restrict__ w2, const float* __restrict__ b2p,
    float* __restrict__ out) {
    __shared__ float Ps[16][401];
    __shared__ float Qs[16][401];
    __shared__ float w2s[400];
    const int tid = threadIdx.x;
    const int i0 = blockIdx.y * 16, j0 = blockIdx.x * 16;
    for (int r = 0; r < 16; r++) {
        for (int k = tid; k < MLP_H; k += 256) {
            Ps[r][k] = pi[(size_t)(i0 + r) * MLP_H + k];
            Qs[r][k] = pj[(size_t)(j0 + r) * MLP_H + k];
        }
    }
    for (int k = tid; k < MLP_H; k += 256) w2s[k] = w2[k];
    __syncthreads();
    const int ti = tid >> 4, tj = tid & 15;
    float acc = 0.f;
#pragma unroll 4
    for (int k = 0; k < MLP_H; k++) {
        float x = Ps[ti][k] + Qs[tj][k];
        acc = fmaf(w2s[k], tanhf_fast(x), acc);
    }
    const int i = i0 + ti, j = j0 + tj;
    out[(size_t)i * T + j] = (i == j) ? 0.f : (acc + b2p[0]);
}

extern "C" void kernel_launch(void* const* d_in, const int* in_sizes, int n_in,
                              void* d_out, int out_size, void* d_ws, size_t ws_size,
                              hipStream_t stream) {
    const int*   words = (const int*)d_in[0];
    const int*   tags  = (const int*)d_in[1];
    const float* wemb  = (const float*)d_in[2];
    const float* temb  = (const float*)d_in[3];
    const float* Wih0  = (const float*)d_in[4];
    const float* Whh0  = (const float*)d_in[5];
    const float* bih0  = (const float*)d_in[6];
    const float* bhh0  = (const float*)d_in[7];
    const float* Wih1  = (const float*)d_in[8];
    const float* Whh1  = (const float*)d_in[9];
    const float* bih1  = (const float*)d_in[10];
    const float* bhh1  = (const float*)d_in[11];
    const float* W1    = (const float*)d_in[12];
    const float* b1    = (const float*)d_in[13];
    const float* W2    = (const float*)d_in[14];
    const float* b2    = (const float*)d_in[15];
    const float* h0    = (const float*)d_in[16];
    const float* c0    = (const float*)d_in[17];
    float* out = (float*)d_out;

    float* W = (float*)d_ws;
    float* x0   = W;                 // 256*400 (dead after layer-0 GEMMs)
    float* x1   = W + 102400;        // 256*800
    float* hvec = W + 307200;        // 256*800
    float* Gb   = W + 512000;        // 2*256*1600 (reused for both layers)
    float* pi   = W + 1331200;       // 256*400
    float* pj   = W + 1433600;       // 256*400 (pj = pi + 102400)
    // word arrays overlap x0's region (x0 dead before lstm_init5 runs)
    u64* slotsA = (u64*)W;                               // 800 u64
    u64* slotsB = (u64*)(W + 2048);                      // 800 u64

    // 1. embedding gather
    gather_k<<<T, 128, 0, stream>>>(words, tags, wemb, temb, x0);

    // 2. layer-0 gate inputs, BOTH dirs in one launch (z = dir)
    gemm_tnz<<<dim3(4, 25, 2), 256, 0, stream>>>(
        x0, H, Wih0, (long)G4 * H, H, 0, 0,
        bih0, G4, 3, bhh0, G4, 3,
        Gb, G4, (long)T * G4, G4, H);

    // 3. init tagged words (x0 now dead), then LSTM layer 0
    lstm_init5<<<1, 256, 0, stream>>>(h0, slotsA, slotsB);
    lstm_layer8<<<2 * NBLK_D, 512, 0, stream>>>(Gb, Whh0, c0, x1, slotsA);

    // 4. layer-1 gate inputs (K=800), BOTH dirs in one launch
    gemm_tnz<<<dim3(4, 25, 2), 256, 0, stream>>>(
        x1, 2 * H, Wih1, (long)G4 * 2 * H, 2 * H, 0, 0,
        bih1, G4, 3, bhh1, G4, 3,
        Gb, G4, (long)T * G4, G4, 2 * H);

    // 5. LSTM layer 1
    lstm_layer8<<<2 * NBLK_D, 512, 0, stream>>>(Gb, Whh1, c0 + 2 * H, hvec, slotsB);

    // 6. pi and pj in ONE launch (z: 0 -> pi with b1, 1 -> pj, W1 col-offset 2H)
    gemm_tnz<<<dim3(4, 7, 2), 256, 0, stream>>>(
        hvec, 2 * H, W1, 0L, G4, 0, 2 * H,
        b1, 0, 1, nullptr, 0, 0,
        pi, MLP_H, 102400L, MLP_H, 2 * H);

    // 7. fused pairwise scores
    scores_k<<<dim3(16, 16), 256, 0, stream>>>(pi, pj, W2, b2, out);
}